// Round 7
// baseline (252.938 us; speedup 1.0000x reference)
//
#include <hip/hip_runtime.h>

// QuantumRecurrentUnit, exact Heisenberg closed form.
//   rev_q = (p_q + x_q)/2pi ;  sa=sin, ca=cos of the angle
//   p_q' = cos(th_q)*prefixprod_{j<=q} ca_j - sin(th_q)*(q<5 ? sa_q*sa_{q+1} : sa_5)
//
// v8: S=16 -- the optimum of the measured throughput curve.
// Seven rounds fit: chip rate R(waves/CU) = 36K lane-steps/us @2 w/CU, 46K @4,
// 85-100K @8, 114K @18 (saturating). Wall = work/R, work = B*T*(W+S)/S.
// v6/v7 minimized work but starved R; v1/v4 fed R but paid 5-9x burn-in tax.
// S=16: work 6.29M lane-steps, 131K windows = 2048 waves = 8 w/CU = the knee.
// Predicted ~65-74 us.
// Structure (verified v6/v7 machinery):
//   - one chain per 64-thread block: chain = blockIdx, window k = lane.
//     All 3x redundant row reads (lanes k,k+1,k+2 touch row 16k+i at steps
//     16 apart) stay in one CU's L1/L2.
//   - zero LDS / zero sync; per-lane row loads (float4+float2, one 64-B line),
//     G=8 double-buffered RAW register groups, sched_barrier(0) fences.
//   - scaled-state trick: state P = p/2pi, cthS/sthS prefolded with 1/2pi ->
//     rev = fma(x_raw, 1/2pi, P); buffers are pure load destinations (no VALU
//     on load results until use -> counted vmcnt at first use, deep overlap).
//     Output rescaled by 2pi on the 16 output steps only.
//   - clamp-to-row-0 burn-in + exact P=0 reset when a window crosses t=0
//     (k=0 at i=32, k=1 at i=16; k>=2 start at t>=0: verified W=32 contraction).
//   - paired float4 stores: pair base = row 16k+even -> byte 384k+48m, aligned.
//   - launch_bounds(64,2): 256-VGPR budget (no allocator crush).

constexpr int T = 1024;
constexpr int NQ = 6;
constexpr int S = 16;        // output steps per window
constexpr int W = 32;        // burn-in steps (accuracy knob -- unchanged)
constexpr int TOT = W + S;   // 48
constexpr int G = 8;         // rows per prefetch group
constexpr int NG = TOT / G;  // 6
constexpr int WPC = T / S;   // 64 windows per chain == blockDim
constexpr float INV2PI = 0.15915494309189535f;  // v_sin/v_cos take revolutions
constexpr float TWOPI = 6.283185307179586f;

__global__ __launch_bounds__(64, 2) void qru_kernel(const float* __restrict__ x,
                                                    const float* __restrict__ w,
                                                    float* __restrict__ out) {
  const int k = threadIdx.x;                     // window index in chain, 0..63
  const int chain = blockIdx.x;
  const float* __restrict__ xb = x + (size_t)chain * (T * 16);
  float* __restrict__ ob = out + (size_t)chain * (T * NQ);
  const int tbase = k * S - W;                   // k=0: -32, k=1: -16

  float cthS[NQ], sthS[NQ];                      // prefolded with 1/2pi
#pragma unroll
  for (int q = 0; q < NQ; ++q) {
    const float th = w[q];
    cthS[q] = cosf(th) * INV2PI;
    sthS[q] = sinf(th) * INV2PI;
  }

  float P[NQ];                                   // scaled state: p/2pi
#pragma unroll
  for (int q = 0; q < NQ; ++q) P[q] = 0.0f;

  float bufA[G][NQ], bufB[G][NQ];                // RAW angle row-groups
  float sv[NQ];                                  // buffered even output row (x 2pi)

  // Load rows [GI*G, GI*G+G) of this window into BUF (raw, untouched).
#define LOADG(GI, BUF)                                                         \
  do {                                                                         \
    _Pragma("unroll") for (int r_ = 0; r_ < G; ++r_) {                         \
      int row_ = tbase + (GI) * G + r_;                                        \
      row_ = row_ < 0 ? 0 : row_; /* burn-in underrun: dummy row 0 */          \
      const float* rp_ = xb + (size_t)row_ * 16;                               \
      const float4 v4_ = *(const float4*)rp_;                                  \
      const float2 v2_ = *(const float2*)(rp_ + 4);                            \
      BUF[r_][0] = v4_.x;                                                      \
      BUF[r_][1] = v4_.y;                                                      \
      BUF[r_][2] = v4_.z;                                                      \
      BUF[r_][3] = v4_.w;                                                      \
      BUF[r_][4] = v2_.x;                                                      \
      BUF[r_][5] = v2_.y;                                                      \
    }                                                                          \
  } while (0)

  // Compute the G steps of group GI from BUF (all indices compile-time).
#define STEPS(GI, BUF)                                                         \
  do {                                                                         \
    _Pragma("unroll") for (int j_ = 0; j_ < G; ++j_) {                         \
      const int i_ = (GI) * G + j_;                                            \
      if (i_ >= S && i_ <= W && (i_ % S) == 0) {                               \
        const bool rs_ = (tbase + i_ == 0); /* crossed t=0: exact restart */   \
        _Pragma("unroll") for (int q_ = 0; q_ < NQ; ++q_)                      \
            P[q_] = rs_ ? 0.0f : P[q_];                                        \
      }                                                                        \
      float sa_[NQ], ca_[NQ];                                                  \
      _Pragma("unroll") for (int q_ = 0; q_ < NQ; ++q_) {                      \
        const float rev_ = fmaf(BUF[j_][q_], INV2PI, P[q_]);                   \
        sa_[q_] = __builtin_amdgcn_sinf(rev_);                                 \
        ca_[q_] = __builtin_amdgcn_cosf(rev_);                                 \
      }                                                                        \
      const float t01_ = ca_[0] * ca_[1];                                      \
      const float t23_ = ca_[2] * ca_[3];                                      \
      const float t45_ = ca_[4] * ca_[5];                                      \
      const float P2_ = t01_ * ca_[2];                                         \
      const float P3_ = t01_ * t23_;                                           \
      const float P4_ = P3_ * ca_[4];                                          \
      const float P5_ = P3_ * t45_;                                            \
      P[0] = cthS[0] * ca_[0] - sthS[0] * (sa_[0] * sa_[1]);                   \
      P[1] = cthS[1] * t01_ - sthS[1] * (sa_[1] * sa_[2]);                     \
      P[2] = cthS[2] * P2_ - sthS[2] * (sa_[2] * sa_[3]);                      \
      P[3] = cthS[3] * P3_ - sthS[3] * (sa_[3] * sa_[4]);                      \
      P[4] = cthS[4] * P4_ - sthS[4] * (sa_[4] * sa_[5]);                      \
      P[5] = cthS[5] * P5_ - sthS[5] * sa_[5];                                 \
      if (i_ >= W) { /* uniform: i_ is compile-time */                         \
        if (((i_ - W) & 1) == 0) { /* even output step: buffer row (x 2pi) */  \
          _Pragma("unroll") for (int q_ = 0; q_ < NQ; ++q_)                    \
              sv[q_] = P[q_] * TWOPI;                                          \
        } else { /* odd: emit rows i_-1,i_ as 3x float4 (48 B, 16B-aligned) */ \
          const float o0_ = P[0] * TWOPI, o1_ = P[1] * TWOPI;                  \
          const float o2_ = P[2] * TWOPI, o3_ = P[3] * TWOPI;                  \
          const float o4_ = P[4] * TWOPI, o5_ = P[5] * TWOPI;                  \
          float* bp_ = ob + (size_t)(tbase + i_ - 1) * NQ;                     \
          *(float4*)(bp_ + 0) = make_float4(sv[0], sv[1], sv[2], sv[3]);       \
          *(float4*)(bp_ + 4) = make_float4(sv[4], sv[5], o0_, o1_);           \
          *(float4*)(bp_ + 8) = make_float4(o2_, o3_, o4_, o5_);               \
        }                                                                      \
      }                                                                        \
    }                                                                          \
  } while (0)

  LOADG(0, bufA);
#pragma unroll
  for (int gi = 0; gi < NG; gi += 2) {  // fully unrolled; gi compile-time
    if (gi + 1 < NG) LOADG(gi + 1, bufB);
    __builtin_amdgcn_sched_barrier(0);  // loads stay batched ahead of compute
    STEPS(gi, bufA);
    if (gi + 2 < NG) LOADG(gi + 2, bufA);
    __builtin_amdgcn_sched_barrier(0);
    STEPS(gi + 1, bufB);
  }
#undef LOADG
#undef STEPS
}

extern "C" void kernel_launch(void* const* d_in, const int* in_sizes, int n_in,
                              void* d_out, int out_size, void* d_ws, size_t ws_size,
                              hipStream_t stream) {
  const float* x = (const float*)d_in[0];
  const float* w = (const float*)d_in[1];
  float* out = (float*)d_out;
  const int chains = in_sizes[0] / (T * 16);        // 2048
  qru_kernel<<<chains, WPC, 0, stream>>>(x, w, out);  // one chain per wave
}

// Round 8
// 222.367 us; speedup vs baseline: 1.1375x; 1.1375x over previous
//
#include <hip/hip_runtime.h>

// QuantumRecurrentUnit, exact Heisenberg closed form.
//   rev_q = (p_q + x_q)/2pi ;  sa=sin, ca=cos of the angle
//   p_q' = cos(th_q)*prefixprod_{j<=q} ca_j - sin(th_q)*(q<5 ? sa_q*sa_{q+1} : sa_5)
//
// v9: chain-per-wave, REGISTER-RESIDENT, shuffle-based burn-in.
// Session model: scatter designs are request-rate-bound (~2.4 TB/s apparent,
// v8 = 258 MB -> 109 us at the ceiling); LDS designs cap at 6 chains/CU
// (25 KB/chain) cancelling work reduction; compute is cheap (<=21% VALUBusy
// ever). So: per-step operands must live in REGISTERS, global traffic must be
// one-time compulsory, waves >= 2/SIMD.
//   - one 64-lane wave per chain; lane l = window l (S=16). Lane l owns rows
//     16l..16l+15 in f[16][6] = 96 VGPRs, loaded once (65 MB total fetch).
//   - burn-in step i<32 reads row 16l+i-32 = slot (i-32)&15 (COMPILE-TIME) of
//     lane l+((i-32)>>4) (uniform shift) -> 6 ds_bpermute per step. No LDS
//     allocation, no per-step global loads. Output steps i>=32: own registers.
//   - lanes 0,1 shuffle wrapped junk during pre-t=0 burn-in; erased by the
//     established exact P=0 reset at i=16 (lane 1) / i=32 (lane 0).
//   - v2's crush fixed: 64-thread block + __launch_bounds__(64,1) = 256-VGPR
//     budget for the ~155-reg live set; every f[] index compile-time.
//   - scaled state P = p/2pi (v8 trick), output x 2pi at stores; paired
//     float4 stores (pair base byte = 384l + 48t, 16B-aligned).

constexpr int T = 1024;
constexpr int NQ = 6;
constexpr int S = 16;        // output steps per lane (= rows owned per lane)
constexpr int W = 32;        // burn-in steps (accuracy knob -- unchanged)
constexpr int TOT = W + S;   // 48
constexpr float INV2PI = 0.15915494309189535f;  // v_sin/v_cos take revolutions
constexpr float TWOPI = 6.283185307179586f;

__global__ __launch_bounds__(64, 1) void qru_kernel(const float* __restrict__ x,
                                                    const float* __restrict__ w,
                                                    float* __restrict__ out) {
  const int l = threadIdx.x;                     // lane = window index, 0..63
  const int chain = blockIdx.x;
  const float* __restrict__ xb = x + (size_t)chain * (T * 16);
  float* __restrict__ ob = out + (size_t)chain * (T * NQ);
  const int tbase = l * S - W;                   // l=0: -32, l=1: -16

  // ---- one-time load: own 16 rows into registers (96 VGPRs) ----
  // 32 VMEM instrs issued up-front; compiler drains vmcnt progressively at
  // first use (step m's shuffle touches f[m]).
  float f[S][NQ];
#pragma unroll
  for (int m = 0; m < S; ++m) {
    const float* rp = xb + (size_t)(l * S + m) * 16;
    const float4 v4 = *(const float4*)rp;
    const float2 v2 = *(const float2*)(rp + 4);
    f[m][0] = v4.x;
    f[m][1] = v4.y;
    f[m][2] = v4.z;
    f[m][3] = v4.w;
    f[m][4] = v2.x;
    f[m][5] = v2.y;
  }

  float cthS[NQ], sthS[NQ];                      // prefolded with 1/2pi
#pragma unroll
  for (int q = 0; q < NQ; ++q) {
    const float th = w[q];
    cthS[q] = cosf(th) * INV2PI;
    sthS[q] = sinf(th) * INV2PI;
  }

  float P[NQ];                                   // scaled state: p/2pi
#pragma unroll
  for (int q = 0; q < NQ; ++q) P[q] = 0.0f;

  float sv[NQ];                                  // buffered even output row (x 2pi)

#pragma unroll
  for (int i = 0; i < TOT; ++i) {                // fully unrolled; i compile-time
    // exact restart when this lane's window crosses t=0 (lane 1 at i=16,
    // lane 0 at i=32) -- wipes the junk burn-in state exactly.
    if (i >= S && i <= W && (i % S) == 0) {
      const bool rs = (tbase + i == 0);
#pragma unroll
      for (int q = 0; q < NQ; ++q) P[q] = rs ? 0.0f : P[q];
    }

    // fetch this step's 6 raw angles: neighbor registers (burn-in) or own.
    float a[NQ];
    if (i < W) {
      const int src = l + ((i - W) >> 4);        // l-2 or l-1 (uniform shift)
      constexpr_int_workaround:;
#pragma unroll
      for (int q = 0; q < NQ; ++q) a[q] = __shfl(f[(i - W) & 15][q], src, 64);
    } else {
#pragma unroll
      for (int q = 0; q < NQ; ++q) a[q] = f[i - W][q];
    }

    float sa[NQ], ca[NQ];
#pragma unroll
    for (int q = 0; q < NQ; ++q) {
      const float rev = fmaf(a[q], INV2PI, P[q]);
      sa[q] = __builtin_amdgcn_sinf(rev);
      ca[q] = __builtin_amdgcn_cosf(rev);
    }
    const float t01 = ca[0] * ca[1];
    const float t23 = ca[2] * ca[3];
    const float t45 = ca[4] * ca[5];
    const float P2 = t01 * ca[2];
    const float P3 = t01 * t23;
    const float P4 = P3 * ca[4];
    const float P5 = P3 * t45;
    P[0] = cthS[0] * ca[0] - sthS[0] * (sa[0] * sa[1]);
    P[1] = cthS[1] * t01 - sthS[1] * (sa[1] * sa[2]);
    P[2] = cthS[2] * P2 - sthS[2] * (sa[2] * sa[3]);
    P[3] = cthS[3] * P3 - sthS[3] * (sa[3] * sa[4]);
    P[4] = cthS[4] * P4 - sthS[4] * (sa[4] * sa[5]);
    P[5] = cthS[5] * P5 - sthS[5] * sa[5];

    if (i >= W) {                                // uniform: i compile-time
      if (((i - W) & 1) == 0) {                  // even output step: buffer
#pragma unroll
        for (int q = 0; q < NQ; ++q) sv[q] = P[q] * TWOPI;
      } else {                                   // odd: emit rows i-1,i
        const float o0 = P[0] * TWOPI, o1 = P[1] * TWOPI;
        const float o2 = P[2] * TWOPI, o3 = P[3] * TWOPI;
        const float o4 = P[4] * TWOPI, o5 = P[5] * TWOPI;
        float* bp = ob + (size_t)(tbase + i - 1) * NQ;  // byte 384l+48t: aligned
        *(float4*)(bp + 0) = make_float4(sv[0], sv[1], sv[2], sv[3]);
        *(float4*)(bp + 4) = make_float4(sv[4], sv[5], o0, o1);
        *(float4*)(bp + 8) = make_float4(o2, o3, o4, o5);
      }
    }
  }
}

extern "C" void kernel_launch(void* const* d_in, const int* in_sizes, int n_in,
                              void* d_out, int out_size, void* d_ws, size_t ws_size,
                              hipStream_t stream) {
  const float* x = (const float*)d_in[0];
  const float* w = (const float*)d_in[1];
  float* out = (float*)d_out;
  const int chains = in_sizes[0] / (T * 16);     // 2048
  qru_kernel<<<chains, 64, 0, stream>>>(x, w, out);  // one wave per chain
}